// Round 18
// baseline (230.030 us; speedup 1.0000x reference)
//
#include <hip/hip_runtime.h>
#include <math.h>

#define LSLOPE 0.01f

__device__ __forceinline__ float lrelu(float x){ return x >= 0.f ? x : LSLOPE * x; }

typedef __attribute__((ext_vector_type(8))) short short8;
typedef __attribute__((ext_vector_type(4))) float f32x4;

__device__ __forceinline__ unsigned short f2bf(float f){
  union { float f; unsigned u; } v; v.f = f;
  unsigned r = v.u + 0x7FFFu + ((v.u >> 16) & 1u);
  return (unsigned short)(r >> 16);
}

__device__ __forceinline__ void gload_lds16(const unsigned short* g, unsigned short* l){
  __builtin_amdgcn_global_load_lds((const __attribute__((address_space(1))) unsigned int*)(g),
                                   (__attribute__((address_space(3))) unsigned int*)(l), 16, 0, 0);
}

constexpr int B    = 16;
constexpr int CIN  = 256;
constexpr int COUT = 256;
constexpr int HH   = 64;
constexpr int WW   = 64;
constexpr int FD   = 128;
constexpr int LAT  = 128;
constexpr int WPS  = CIN * 9;           // 2304
constexpr int WTOT = COUT * WPS;        // 589824
constexpr int HP   = 66;                // padded spatial dim

// ---- workspace layout (in floats) ----
constexpr int OFF_STAT  = 0;                        // [2]
constexpr int OFF_BMEAN = 16;                       // [16]
constexpr int OFF_BSTD  = 32;                       // [16]
constexpr int OFF_P     = 64;                       // [11][8][2304] partial coeffs
constexpr int OFF_STYLE = OFF_P + 11 * 8 * WPS;     // [16*4608]
constexpr int OFF_NBIAS = OFF_STYLE + B * 2 * WPS;  // [16*256]
constexpr int OFF_NW    = OFF_NBIAS + B * COUT;     // bf16 [16][9][256][256]
constexpr int OFF_YTR   = OFF_NW + (B * 9 * COUT * CIN) / 2;   // bf16 [16][66][66][256]

constexpr int PADT = 264;
constexpr int NB_YT = HP * B;        // 1056 (dispatched first: the long pole)
constexpr int NB_CF = 72;            // 9 rem-blocks x 8 oc-chunks
constexpr int NB_SB = B * 18 + B;    // 304
// prep1 grid = 1056 + 72 + 304 = 1432

// ---------- fused prep1: y transpose | coeff partials -> P | style MLP + bias ----------
__global__ __launch_bounds__(256) void k_prep1(const float* __restrict__ y, unsigned short* __restrict__ ytrp,
                                               const float* __restrict__ ow, const float* __restrict__ fwgt,
                                               const float* __restrict__ wmask, float* __restrict__ P,
                                               const float* __restrict__ finger, const float* __restrict__ sw1,
                                               const float* __restrict__ sw2, float* __restrict__ style,
                                               const float* __restrict__ bw1, const float* __restrict__ bw2,
                                               const float* __restrict__ fbias, const float* __restrict__ bmask,
                                               const float* __restrict__ obias, float* __restrict__ nbias){
  __shared__ __align__(16) char shraw[64 * PADT * 2];   // 33792 B
  const int blk = blockIdx.x;
  const int tid = threadIdx.x;

  if (blk < NB_YT){
    // ---- y -> channel-last bf16 with zero halo ----
    unsigned short* t = (unsigned short*)shraw;
    const int ghp = blk % HP, b = blk / HP;
    unsigned short* dst = ytrp + ((size_t)b * HP + ghp) * HP * CIN;
    if (ghp == 0 || ghp == HP - 1){
      for (int c = tid; c < HP * CIN / 8; c += 256) ((uint4*)dst)[c] = (uint4){0, 0, 0, 0};
      return;
    }
    const int h = ghp - 1;
    const float* src = y + (size_t)b * CIN * HH * WW + h * WW;
    #pragma unroll
    for (int k = 0; k < 16; ++k){
      int idx = tid + k * 256;
      int ic = idx >> 4, w4 = (idx & 15) * 4;
      float4 v = *(const float4*)(src + (size_t)ic * HH * WW + w4);
      t[(w4 + 0) * PADT + ic] = f2bf(v.x);
      t[(w4 + 1) * PADT + ic] = f2bf(v.y);
      t[(w4 + 2) * PADT + ic] = f2bf(v.z);
      t[(w4 + 3) * PADT + ic] = f2bf(v.w);
    }
    __syncthreads();
    for (int c = tid; c < HP * CIN / 8; c += 256){
      int gwp = c >> 5, icg = (c & 31) * 8;
      uint4 v = (uint4){0, 0, 0, 0};
      if (gwp >= 1 && gwp <= 64) v = *(const uint4*)(&t[(gwp - 1) * PADT + icg]);
      ((uint4*)dst)[c] = v;
    }
  } else if (blk < NB_YT + NB_CF){
    // ---- coefficient partials over a 32-oc chunk ----
    const int cb = blk - NB_YT;           // 0..71
    const int rb = cb % 9, ob = cb / 9;   // rem-block, oc-chunk
    const int rem = rb * 256 + tid;
    const int ic = rem / 9;
    float a_ow = 0.f, q_ow = 0.f, ab = 0.f, qb = 0.f;
    float a1 = 0.f, a2 = 0.f, d1 = 0.f, d2 = 0.f, d3 = 0.f, d4 = 0.f, d5 = 0.f;
    for (int oc = ob * 32; oc < ob * 32 + 32; ++oc){
      float w = ow[(size_t)oc * WPS + rem];
      float f = fwgt[(size_t)oc * WPS + rem];
      float m = wmask[oc * CIN + ic];
      float fw = (6.f - fminf(fmaxf(m, 0.f), 6.f)) * (1.f / 6.f);
      float base = w + fw * (f - w);
      float c1 = fw * f, c2 = fw;
      a_ow += w; q_ow += w * w;
      ab += base; qb += base * base;
      a1 += c1; a2 += c2;
      d1 += c1 * c1; d2 += c2 * c2; d3 += base * c1; d4 += base * c2; d5 += c1 * c2;
    }
    float* p = P + (size_t)ob * WPS + rem;
    p[(size_t)0  * 8 * WPS] = a_ow; p[(size_t)1  * 8 * WPS] = q_ow;
    p[(size_t)2  * 8 * WPS] = ab;   p[(size_t)3  * 8 * WPS] = qb;
    p[(size_t)4  * 8 * WPS] = a1;   p[(size_t)5  * 8 * WPS] = a2;
    p[(size_t)6  * 8 * WPS] = d1;   p[(size_t)7  * 8 * WPS] = d2;
    p[(size_t)8  * 8 * WPS] = d3;   p[(size_t)9  * 8 * WPS] = d4;
    p[(size_t)10 * 8 * WPS] = d5;
  } else {
    // ---- style MLP / bias ----
    float* sh = (float*)shraw;
    const int blk2 = blk - NB_YT - NB_CF;
    if (blk2 < B * 18){
      const int b = blk2 / 18, j0 = (blk2 - b * 18) * 256;
      if (tid < LAT){
        float a = 0.f;
        const float* fg = finger + b * FD;
        const float* w = sw1 + (size_t)tid * FD;
        for (int f = 0; f < FD; ++f) a += fg[f] * w[f];
        sh[tid] = lrelu(a);
      }
      __syncthreads();
      const int j = j0 + tid;
      float a = 0.f;
      const float* w2 = sw2 + (size_t)j * LAT;
      for (int l = 0; l < LAT; ++l) a += sh[l] * w2[l];
      style[(size_t)b * 2 * WPS + j] = a;
    } else {
      const int b = blk2 - B * 18, o = tid;
      float acc = 0.f;
      for (int f = 0; f < FD; ++f) acc += finger[b * FD + f] * bw1[o * FD + f];
      sh[o] = lrelu(acc);
      __syncthreads();
      float t = 0.f;
      for (int c = 0; c < COUT; ++c) t += sh[c] * bw2[o * COUT + c];
      t = lrelu(t);
      float sb = fbias[o] * t;
      float fwb = (6.f - fminf(fmaxf(bmask[o], 0.f), 6.f)) * (1.f / 6.f);
      nbias[b * COUT + o] = (1.f - fwb) * obias[o] + fwb * sb;
    }
  }
}

// ---------- per-b stats from partial coefficients (8-way reduce inline) ----------
__global__ __launch_bounds__(256) void k_wstats(const float* __restrict__ P, const float* __restrict__ style,
                                                float* stat, float* bmean, float* bstd){
  __shared__ float rs[4][4];
  const int b = blockIdx.x, tid = threadIdx.x;
  const int lane = tid & 63, wid = tid >> 6;
  const float* st = style + (size_t)b * 2 * WPS;
  float s = 0.f, q = 0.f, so = 0.f, qo = 0.f;
  for (int k = 0; k < 9; ++k){
    int rem = k * 256 + tid;
    float c[11];
    #pragma unroll
    for (int a = 0; a < 11; ++a){
      float v = 0.f;
      #pragma unroll
      for (int ob = 0; ob < 8; ++ob) v += P[((size_t)a * 8 + ob) * WPS + rem];
      c[a] = v;
    }
    float s0 = st[rem], s1 = st[WPS + rem];
    so += c[0]; qo += c[1];
    s += c[2] + s0 * c[4] + s1 * c[5];
    q += c[3] + s0 * s0 * c[6] + s1 * s1 * c[7] + 2.f * (s0 * c[8] + s1 * c[9] + s0 * s1 * c[10]);
  }
  for (int o = 32; o > 0; o >>= 1){
    s += __shfl_down(s, o); q += __shfl_down(q, o);
    so += __shfl_down(so, o); qo += __shfl_down(qo, o);
  }
  if (lane == 0){ rs[0][wid] = s; rs[1][wid] = q; rs[2][wid] = so; rs[3][wid] = qo; }
  __syncthreads();
  if (tid == 0){
    const float N = (float)WTOT;
    float S = rs[0][0] + rs[0][1] + rs[0][2] + rs[0][3];
    float Q = rs[1][0] + rs[1][1] + rs[1][2] + rs[1][3];
    bmean[b] = S / N;
    bstd[b]  = sqrtf((Q - S * S / N) / (N - 1.f));
    if (b == 0){
      float SO = rs[2][0] + rs[2][1] + rs[2][2] + rs[2][3];
      float QO = rs[3][0] + rs[3][1] + rs[3][2] + rs[3][3];
      stat[0] = SO / N;
      stat[1] = sqrtf((QO - SO * SO / N) / (N - 1.f));
    }
  }
}

// ---------- materialize new_weight bf16 [b][t][oc][ic]; 2 samples per block ----------
__global__ __launch_bounds__(256) void k_new_weight4(const float* __restrict__ ow, const float* __restrict__ fwgt,
                                                     const float* __restrict__ wmask, const float* __restrict__ style,
                                                     const float* __restrict__ stat, const float* __restrict__ bmean,
                                                     const float* __restrict__ bstd, unsigned short* __restrict__ nw){
  __shared__ float ows[WPS];
  __shared__ float fws[WPS];
  __shared__ float sts[2 * WPS];
  const int bi = blockIdx.x, oc = blockIdx.y;
  const int tid = threadIdx.x;               // = ic
  const float mean_ori = stat[0], std_ori = stat[1];
  const float4* owr4 = (const float4*)(ow + (size_t)oc * WPS);
  const float4* fwr4 = (const float4*)(fwgt + (size_t)oc * WPS);
  #pragma unroll
  for (int i = 0; i < 3; ++i){
    int idx = tid + i * 256;
    if (idx < WPS / 4){
      ((float4*)ows)[idx] = owr4[idx];
      ((float4*)fws)[idx] = fwr4[idx];
    }
  }
  const float fw = (6.f - fminf(fmaxf(wmask[oc * CIN + tid], 0.f), 6.f)) * (1.f / 6.f);
  #pragma unroll
  for (int bb = 0; bb < 2; ++bb){
    const int b = bi * 2 + bb;
    __syncthreads();
    const float4* st4 = (const float4*)(style + (size_t)b * 2 * WPS);
    #pragma unroll
    for (int i = 0; i < 5; ++i){
      int idx = tid + i * 256;
      if (idx < 2 * WPS / 4) ((float4*)sts)[idx] = st4[idx];
    }
    __syncthreads();
    const float bm = bmean[b], bs = bstd[b];
    #pragma unroll
    for (int t = 0; t < 9; ++t){
      int rem = tid * 9 + t;
      float owv = ows[rem];
      float sw = fws[rem] * (sts[rem] + 1.f) + sts[WPS + rem];
      float w1 = owv + fw * (sw - owv);
      float w2 = (w1 - bm) / bs * std_ori + mean_ori;
      nw[((size_t)(b * 9 + t) * COUT + oc) * CIN + tid] = f2bf(owv + fw * (w2 - owv));
    }
  }
}

// ---------- MFMA conv: 128oc x 256hw block, 64x128/wave, single-buffer LDS ----------
// Proven champion: 2 blocks/CU, XCD b-pinning, DMA staging, XOR chunk swizzle.
__global__ __launch_bounds__(256, 2) void k_conv_mfma11(const unsigned short* __restrict__ ytrp,
                                                        const unsigned short* __restrict__ nw,
                                                        const float* __restrict__ nbias,
                                                        float* __restrict__ out){
  __shared__ __align__(16) unsigned short Wa[3 * 128 * 32];   // 24576 B
  __shared__ __align__(16) unsigned short Yt[288 * 32];       // 18432 B
  __shared__ float bsh[128];

  const int bid = blockIdx.x;
  const int xcd = bid & 7;
  const int b   = ((bid >> 8) << 3) | xcd;   // 0..15, pinned to xcd
  const int oc0 = ((bid >> 3) & 1) * 128;
  const int hwt = (bid >> 4) & 15;
  const int tid = threadIdx.x;
  const int lane = tid & 63, wid = tid >> 6;
  const int wr = wid >> 1, wc = wid & 1;   // wr: oc half (64), wc: hw half (128)
  const int hw0 = hwt * 256;
  const int h0  = hwt * 4;

  if (tid < 128) bsh[tid] = nbias[b * COUT + oc0 + tid];

  f32x4 acc[4][8];
  #pragma unroll
  for (int i = 0; i < 4; ++i)
    #pragma unroll
    for (int j = 0; j < 8; ++j) acc[i][j] = (f32x4){0.f, 0.f, 0.f, 0.f};

  const unsigned short* nwb = nw + ((size_t)(b * 9) * COUT + oc0) * CIN;
  const unsigned short* ytb = ytrp + (size_t)b * HP * HP * CIN;

  // ---- A DMA: 24 issues of 16 rows; wave takes I = wid + 4s, s<6 ----
  int a_tap[6], a_go[6], a_lo[6];
  #pragma unroll
  for (int s = 0; s < 6; ++s){
    int I = wid + 4 * s;
    int tap = I >> 3, rowbase = (I & 7) * 16;
    int row = rowbase + (lane >> 2), p = lane & 3;
    int g = p ^ ((row >> 1) & 3);
    a_tap[s] = tap;
    a_go[s]  = row * CIN + g * 8;
    a_lo[s]  = (tap * 128 + rowbase) * 32;
  }
  // ---- Y DMA: 288 sites (4 rows x 72), 18 issues of 16; I = wid + 4s, s<5 ----
  int y_go[5], y_lo[5]; bool y_has[5];
  #pragma unroll
  for (int s = 0; s < 5; ++s){
    int I = wid + 4 * s;
    y_has[s] = (I < 18);
    int Ic = y_has[s] ? I : 0;
    int site = Ic * 16 + (lane >> 2);
    int srow = site / 72;
    int scol = site - srow * 72;
    int gwp  = scol > 65 ? 65 : scol;
    int p = lane & 3, g = p ^ ((site >> 1) & 3);
    y_go[s] = ((h0 + srow + 1) * HP + gwp) * CIN + g * 8;
    y_lo[s] = Ic * 16 * 32;
  }

  // ---- fragment read bases ----
  const int gq = lane >> 4;
  int a_rb[4];
  #pragma unroll
  for (int mi = 0; mi < 4; ++mi){
    int r = wr * 64 + mi * 16 + (lane & 15);
    a_rb[mi] = r * 64 + ((gq ^ ((r >> 1) & 3)) << 4);
  }
  int b_site[8];
  #pragma unroll
  for (int ni = 0; ni < 8; ++ni)
    b_site[ni] = (wc * 2 + (ni >> 2)) * 72 + (ni & 3) * 16 + (lane & 15);

  #define STAGE(IT)                                                                 \
    {                                                                               \
      const int dhb = (IT) >> 3;                                                    \
      const int ic0s = ((IT) & 7) * 32;                                             \
      const unsigned short* ybase = ytb + (ptrdiff_t)(dhb - 1) * HP * CIN + ic0s;   \
      _Pragma("unroll")                                                             \
      for (int s = 0; s < 5; ++s)                                                   \
        if (y_has[s]) gload_lds16(ybase + y_go[s], &Yt[0] + y_lo[s]);               \
      const unsigned short* atap = nwb + (size_t)(dhb * 3) * COUT * CIN + ic0s;     \
      _Pragma("unroll")                                                             \
      for (int s = 0; s < 6; ++s)                                                   \
        gload_lds16(atap + (size_t)a_tap[s] * COUT * CIN + a_go[s], &Wa[0] + a_lo[s]); \
    }

  #define COMPUTE()                                                                 \
    {                                                                               \
      const char* wap = (const char*)&Wa[0];                                        \
      const char* ytp = (const char*)&Yt[0];                                        \
      _Pragma("unroll")                                                             \
      for (int tap = 0; tap < 3; ++tap){                                            \
        short8 af[4];                                                               \
        _Pragma("unroll")                                                           \
        for (int mi = 0; mi < 4; ++mi)                                              \
          af[mi] = *(const short8*)(wap + tap * 8192 + a_rb[mi]);                   \
        _Pragma("unroll")                                                           \
        for (int ni = 0; ni < 8; ++ni){                                             \
          const int site = b_site[ni] + tap;                                        \
          const int boff = (site << 6) + ((gq ^ ((site >> 1) & 3)) << 4);           \
          const short8 bf = *(const short8*)(ytp + boff);                           \
          _Pragma("unroll")                                                         \
          for (int mi = 0; mi < 4; ++mi)                                            \
            acc[mi][ni] = __builtin_amdgcn_mfma_f32_16x16x32_bf16(af[mi], bf, acc[mi][ni], 0, 0, 0); \
        }                                                                           \
      }                                                                             \
    }

  #pragma unroll 1
  for (int it = 0; it < 24; ++it){
    __syncthreads();     // previous compute done; safe to overwrite LDS
    STAGE(it);
    __syncthreads();     // DMA drained
    COMPUTE();
  }
  #undef STAGE
  #undef COMPUTE

  // epilogue: D layout col=lane&15 (hw), row=(lane>>4)*4+reg (oc)
  const int col_l = lane & 15, row_l = (lane >> 4) * 4;
  #pragma unroll
  for (int mi = 0; mi < 4; ++mi){
    #pragma unroll
    for (int r = 0; r < 4; ++r){
      const int ocl = wr * 64 + mi * 16 + row_l + r;
      const float bb = bsh[ocl];
      float* op = out + ((size_t)(b * COUT + oc0 + ocl)) * (HH * WW) + hw0 + wc * 128;
      #pragma unroll
      for (int ni = 0; ni < 8; ++ni)
        op[(ni >> 2) * 64 + (ni & 3) * 16 + col_l] = acc[mi][ni][r] + bb;
    }
  }
}

extern "C" void kernel_launch(void* const* d_in, const int* in_sizes, int n_in,
                              void* d_out, int out_size, void* d_ws, size_t ws_size,
                              hipStream_t stream){
  const float* y      = (const float*)d_in[0];
  const float* finger = (const float*)d_in[1];
  const float* ow     = (const float*)d_in[2];
  const float* wmask  = (const float*)d_in[3];
  const float* fwgt   = (const float*)d_in[4];
  const float* sw1    = (const float*)d_in[5];
  const float* sw2    = (const float*)d_in[6];
  const float* obias  = (const float*)d_in[7];
  const float* bmask  = (const float*)d_in[8];
  const float* fbias  = (const float*)d_in[9];
  const float* bw1    = (const float*)d_in[10];
  const float* bw2    = (const float*)d_in[11];
  float* out = (float*)d_out;
  float* ws  = (float*)d_ws;

  float* stat  = ws + OFF_STAT;
  float* bmean = ws + OFF_BMEAN;
  float* bstd  = ws + OFF_BSTD;
  float* P     = ws + OFF_P;
  float* style = ws + OFF_STYLE;
  float* nbias = ws + OFF_NBIAS;
  unsigned short* nw   = (unsigned short*)(ws + OFF_NW);
  unsigned short* ytrp = (unsigned short*)(ws + OFF_YTR);

  k_prep1<<<NB_YT + NB_CF + NB_SB, 256, 0, stream>>>(y, ytrp, ow, fwgt, wmask, P,
                                                     finger, sw1, sw2, style,
                                                     bw1, bw2, fbias, bmask, obias, nbias);
  k_wstats<<<B, 256, 0, stream>>>(P, style, stat, bmean, bstd);
  k_new_weight4<<<dim3(B / 2, COUT), 256, 0, stream>>>(ow, fwgt, wmask, style, stat, bmean, bstd, nw);
  k_conv_mfma11<<<512, 256, 0, stream>>>(ytrp, nw, nbias, out);
}

// Round 19
// 138.688 us; speedup vs baseline: 1.6586x; 1.6586x over previous
//
#include <hip/hip_runtime.h>
#include <math.h>

#define LSLOPE 0.01f

__device__ __forceinline__ float lrelu(float x){ return x >= 0.f ? x : LSLOPE * x; }

typedef __attribute__((ext_vector_type(8))) short short8;
typedef __attribute__((ext_vector_type(4))) float f32x4;

__device__ __forceinline__ unsigned short f2bf(float f){
  union { float f; unsigned u; } v; v.f = f;
  unsigned r = v.u + 0x7FFFu + ((v.u >> 16) & 1u);
  return (unsigned short)(r >> 16);
}

__device__ __forceinline__ void gload_lds16(const unsigned short* g, unsigned short* l){
  __builtin_amdgcn_global_load_lds((const __attribute__((address_space(1))) unsigned int*)(g),
                                   (__attribute__((address_space(3))) unsigned int*)(l), 16, 0, 0);
}

constexpr int B    = 16;
constexpr int CIN  = 256;
constexpr int COUT = 256;
constexpr int HH   = 64;
constexpr int WW   = 64;
constexpr int FD   = 128;
constexpr int LAT  = 128;
constexpr int WPS  = CIN * 9;           // 2304
constexpr int WTOT = COUT * WPS;        // 589824
constexpr int HP   = 66;                // padded spatial dim

// ---- workspace layout (in floats) ----
constexpr int OFF_STAT  = 0;                        // [2]
constexpr int OFF_BMEAN = 16;                       // [16]
constexpr int OFF_BSTD  = 32;                       // [16]
constexpr int OFF_C     = 64;                       // [11][2304]
constexpr int OFF_STYLE = OFF_C + 11 * WPS;         // [16*4608]
constexpr int OFF_NBIAS = OFF_STYLE + B * 2 * WPS;  // [16*256]
constexpr int OFF_NW    = OFF_NBIAS + B * COUT;     // bf16 [16][9][256][256]
constexpr int OFF_YTR   = OFF_NW + (B * 9 * COUT * CIN) / 2;   // bf16 [16][66][66][256]

constexpr int PADT = 264;
constexpr int NB_CF = 9;
constexpr int NB_SB = B * 18 + B;    // 304
constexpr int NB_YT = HP * B;        // 1056

// ---------- fused prep1: coeff->C | style MLP + bias | y transpose ----------
__global__ __launch_bounds__(256) void k_prep1(const float* __restrict__ y, unsigned short* __restrict__ ytrp,
                                               const float* __restrict__ ow, const float* __restrict__ fwgt,
                                               const float* __restrict__ wmask, float* __restrict__ C,
                                               const float* __restrict__ finger, const float* __restrict__ sw1,
                                               const float* __restrict__ sw2, float* __restrict__ style,
                                               const float* __restrict__ bw1, const float* __restrict__ bw2,
                                               const float* __restrict__ fbias, const float* __restrict__ bmask,
                                               const float* __restrict__ obias, float* __restrict__ nbias){
  __shared__ __align__(16) char shraw[64 * PADT * 2];   // 33792 B
  const int blk = blockIdx.x;
  const int tid = threadIdx.x;

  if (blk < NB_CF){
    const int rem = blk * 256 + tid;
    const int ic = rem / 9;
    float a_ow = 0.f, q_ow = 0.f, ab = 0.f, qb = 0.f;
    float a1 = 0.f, a2 = 0.f, d1 = 0.f, d2 = 0.f, d3 = 0.f, d4 = 0.f, d5 = 0.f;
    for (int oc = 0; oc < COUT; ++oc){
      float w = ow[(size_t)oc * WPS + rem];
      float f = fwgt[(size_t)oc * WPS + rem];
      float m = wmask[oc * CIN + ic];
      float fw = (6.f - fminf(fmaxf(m, 0.f), 6.f)) * (1.f / 6.f);
      float base = w + fw * (f - w);
      float c1 = fw * f, c2 = fw;
      a_ow += w; q_ow += w * w;
      ab += base; qb += base * base;
      a1 += c1; a2 += c2;
      d1 += c1 * c1; d2 += c2 * c2; d3 += base * c1; d4 += base * c2; d5 += c1 * c2;
    }
    C[(size_t)0  * WPS + rem] = a_ow; C[(size_t)1  * WPS + rem] = q_ow;
    C[(size_t)2  * WPS + rem] = ab;   C[(size_t)3  * WPS + rem] = qb;
    C[(size_t)4  * WPS + rem] = a1;   C[(size_t)5  * WPS + rem] = a2;
    C[(size_t)6  * WPS + rem] = d1;   C[(size_t)7  * WPS + rem] = d2;
    C[(size_t)8  * WPS + rem] = d3;   C[(size_t)9  * WPS + rem] = d4;
    C[(size_t)10 * WPS + rem] = d5;
  } else if (blk < NB_CF + NB_SB){
    float* sh = (float*)shraw;
    const int blk2 = blk - NB_CF;
    if (blk2 < B * 18){
      const int b = blk2 / 18, j0 = (blk2 - b * 18) * 256;
      if (tid < LAT){
        float a = 0.f;
        const float* fg = finger + b * FD;
        const float* w = sw1 + (size_t)tid * FD;
        for (int f = 0; f < FD; ++f) a += fg[f] * w[f];
        sh[tid] = lrelu(a);
      }
      __syncthreads();
      const int j = j0 + tid;
      float a = 0.f;
      const float* w2 = sw2 + (size_t)j * LAT;
      for (int l = 0; l < LAT; ++l) a += sh[l] * w2[l];
      style[(size_t)b * 2 * WPS + j] = a;
    } else {
      const int b = blk2 - B * 18, o = tid;
      float acc = 0.f;
      for (int f = 0; f < FD; ++f) acc += finger[b * FD + f] * bw1[o * FD + f];
      sh[o] = lrelu(acc);
      __syncthreads();
      float t = 0.f;
      for (int c = 0; c < COUT; ++c) t += sh[c] * bw2[o * COUT + c];
      t = lrelu(t);
      float sb = fbias[o] * t;
      float fwb = (6.f - fminf(fmaxf(bmask[o], 0.f), 6.f)) * (1.f / 6.f);
      nbias[b * COUT + o] = (1.f - fwb) * obias[o] + fwb * sb;
    }
  } else {
    unsigned short* t = (unsigned short*)shraw;
    const int blk3 = blk - NB_CF - NB_SB;
    const int ghp = blk3 % HP, b = blk3 / HP;
    unsigned short* dst = ytrp + ((size_t)b * HP + ghp) * HP * CIN;
    if (ghp == 0 || ghp == HP - 1){
      for (int c = tid; c < HP * CIN / 8; c += 256) ((uint4*)dst)[c] = (uint4){0, 0, 0, 0};
      return;
    }
    const int h = ghp - 1;
    const float* src = y + (size_t)b * CIN * HH * WW + h * WW;
    #pragma unroll
    for (int k = 0; k < 16; ++k){
      int idx = tid + k * 256;
      int ic = idx >> 4, w4 = (idx & 15) * 4;
      float4 v = *(const float4*)(src + (size_t)ic * HH * WW + w4);
      t[(w4 + 0) * PADT + ic] = f2bf(v.x);
      t[(w4 + 1) * PADT + ic] = f2bf(v.y);
      t[(w4 + 2) * PADT + ic] = f2bf(v.z);
      t[(w4 + 3) * PADT + ic] = f2bf(v.w);
    }
    __syncthreads();
    for (int c = tid; c < HP * CIN / 8; c += 256){
      int gwp = c >> 5, icg = (c & 31) * 8;
      uint4 v = (uint4){0, 0, 0, 0};
      if (gwp >= 1 && gwp <= 64) v = *(const uint4*)(&t[(gwp - 1) * PADT + icg]);
      ((uint4*)dst)[c] = v;
    }
  }
}

// ---------- per-b stats from coefficients ----------
__global__ __launch_bounds__(256) void k_wstats(const float* __restrict__ C, const float* __restrict__ style,
                                                float* stat, float* bmean, float* bstd){
  __shared__ float rs[4][4];
  const int b = blockIdx.x, tid = threadIdx.x;
  const int lane = tid & 63, wid = tid >> 6;
  const float* st = style + (size_t)b * 2 * WPS;
  float s = 0.f, q = 0.f, so = 0.f, qo = 0.f;
  for (int k = 0; k < 9; ++k){
    int rem = k * 256 + tid;
    float aow = C[0 * WPS + rem], qow = C[1 * WPS + rem];
    float ab  = C[2 * WPS + rem], qb  = C[3 * WPS + rem];
    float a1  = C[4 * WPS + rem], a2  = C[5 * WPS + rem];
    float d1  = C[6 * WPS + rem], d2  = C[7 * WPS + rem];
    float d3  = C[8 * WPS + rem], d4  = C[9 * WPS + rem], d5 = C[10 * WPS + rem];
    float s0 = st[rem], s1 = st[WPS + rem];
    so += aow; qo += qow;
    s += ab + s0 * a1 + s1 * a2;
    q += qb + s0 * s0 * d1 + s1 * s1 * d2 + 2.f * (s0 * d3 + s1 * d4 + s0 * s1 * d5);
  }
  for (int o = 32; o > 0; o >>= 1){
    s += __shfl_down(s, o); q += __shfl_down(q, o);
    so += __shfl_down(so, o); qo += __shfl_down(qo, o);
  }
  if (lane == 0){ rs[0][wid] = s; rs[1][wid] = q; rs[2][wid] = so; rs[3][wid] = qo; }
  __syncthreads();
  if (tid == 0){
    const float N = (float)WTOT;
    float S = rs[0][0] + rs[0][1] + rs[0][2] + rs[0][3];
    float Q = rs[1][0] + rs[1][1] + rs[1][2] + rs[1][3];
    bmean[b] = S / N;
    bstd[b]  = sqrtf((Q - S * S / N) / (N - 1.f));
    if (b == 0){
      float SO = rs[2][0] + rs[2][1] + rs[2][2] + rs[2][3];
      float QO = rs[3][0] + rs[3][1] + rs[3][2] + rs[3][3];
      stat[0] = SO / N;
      stat[1] = sqrtf((QO - SO * SO / N) / (N - 1.f));
    }
  }
}

// ---------- materialize new_weight bf16 [b][t][oc][ic]; 2 samples per block ----------
// float4-vectorized staging (G13): ow/fwgt rows and style are 16B-aligned.
__global__ __launch_bounds__(256) void k_new_weight4(const float* __restrict__ ow, const float* __restrict__ fwgt,
                                                     const float* __restrict__ wmask, const float* __restrict__ style,
                                                     const float* __restrict__ stat, const float* __restrict__ bmean,
                                                     const float* __restrict__ bstd, unsigned short* __restrict__ nw){
  __shared__ float ows[WPS];
  __shared__ float fws[WPS];
  __shared__ float sts[2 * WPS];
  const int bi = blockIdx.x, oc = blockIdx.y;
  const int tid = threadIdx.x;               // = ic
  const float mean_ori = stat[0], std_ori = stat[1];
  const float4* owr4 = (const float4*)(ow + (size_t)oc * WPS);
  const float4* fwr4 = (const float4*)(fwgt + (size_t)oc * WPS);
  #pragma unroll
  for (int i = 0; i < 3; ++i){                 // 576 float4 total, 256 threads
    int idx = tid + i * 256;
    if (idx < WPS / 4){
      ((float4*)ows)[idx] = owr4[idx];
      ((float4*)fws)[idx] = fwr4[idx];
    }
  }
  const float fw = (6.f - fminf(fmaxf(wmask[oc * CIN + tid], 0.f), 6.f)) * (1.f / 6.f);
  #pragma unroll
  for (int bb = 0; bb < 2; ++bb){
    const int b = bi * 2 + bb;
    __syncthreads();
    const float4* st4 = (const float4*)(style + (size_t)b * 2 * WPS);
    #pragma unroll
    for (int i = 0; i < 5; ++i){               // 1152 float4 total
      int idx = tid + i * 256;
      if (idx < 2 * WPS / 4) ((float4*)sts)[idx] = st4[idx];
    }
    __syncthreads();
    const float bm = bmean[b], bs = bstd[b];
    #pragma unroll
    for (int t = 0; t < 9; ++t){
      int rem = tid * 9 + t;
      float owv = ows[rem];
      float sw = fws[rem] * (sts[rem] + 1.f) + sts[WPS + rem];
      float w1 = owv + fw * (sw - owv);
      float w2 = (w1 - bm) / bs * std_ori + mean_ori;
      nw[((size_t)(b * 9 + t) * COUT + oc) * CIN + tid] = f2bf(owv + fw * (w2 - owv));
    }
  }
}

// ---------- MFMA conv: 128oc x 256hw block, 64x128/wave, single-buffer LDS ----------
// Proven champion (r12/r14/r17): 2 blocks/CU, XCD b-pinning, DMA staging, XOR chunk swizzle.
__global__ __launch_bounds__(256, 2) void k_conv_mfma11(const unsigned short* __restrict__ ytrp,
                                                        const unsigned short* __restrict__ nw,
                                                        const float* __restrict__ nbias,
                                                        float* __restrict__ out){
  __shared__ __align__(16) unsigned short Wa[3 * 128 * 32];   // 24576 B
  __shared__ __align__(16) unsigned short Yt[288 * 32];       // 18432 B
  __shared__ float bsh[128];

  const int bid = blockIdx.x;
  const int xcd = bid & 7;
  const int b   = ((bid >> 8) << 3) | xcd;   // 0..15, pinned to xcd
  const int oc0 = ((bid >> 3) & 1) * 128;
  const int hwt = (bid >> 4) & 15;
  const int tid = threadIdx.x;
  const int lane = tid & 63, wid = tid >> 6;
  const int wr = wid >> 1, wc = wid & 1;   // wr: oc half (64), wc: hw half (128)
  const int hw0 = hwt * 256;
  const int h0  = hwt * 4;

  if (tid < 128) bsh[tid] = nbias[b * COUT + oc0 + tid];

  f32x4 acc[4][8];
  #pragma unroll
  for (int i = 0; i < 4; ++i)
    #pragma unroll
    for (int j = 0; j < 8; ++j) acc[i][j] = (f32x4){0.f, 0.f, 0.f, 0.f};

  const unsigned short* nwb = nw + ((size_t)(b * 9) * COUT + oc0) * CIN;
  const unsigned short* ytb = ytrp + (size_t)b * HP * HP * CIN;

  // ---- A DMA: 24 issues of 16 rows; wave takes I = wid + 4s, s<6 ----
  int a_tap[6], a_go[6], a_lo[6];
  #pragma unroll
  for (int s = 0; s < 6; ++s){
    int I = wid + 4 * s;
    int tap = I >> 3, rowbase = (I & 7) * 16;
    int row = rowbase + (lane >> 2), p = lane & 3;
    int g = p ^ ((row >> 1) & 3);
    a_tap[s] = tap;
    a_go[s]  = row * CIN + g * 8;
    a_lo[s]  = (tap * 128 + rowbase) * 32;
  }
  // ---- Y DMA: 288 sites (4 rows x 72), 18 issues of 16; I = wid + 4s, s<5 ----
  int y_go[5], y_lo[5]; bool y_has[5];
  #pragma unroll
  for (int s = 0; s < 5; ++s){
    int I = wid + 4 * s;
    y_has[s] = (I < 18);
    int Ic = y_has[s] ? I : 0;
    int site = Ic * 16 + (lane >> 2);
    int srow = site / 72;
    int scol = site - srow * 72;
    int gwp  = scol > 65 ? 65 : scol;
    int p = lane & 3, g = p ^ ((site >> 1) & 3);
    y_go[s] = ((h0 + srow + 1) * HP + gwp) * CIN + g * 8;
    y_lo[s] = Ic * 16 * 32;
  }

  // ---- fragment read bases ----
  const int gq = lane >> 4;
  int a_rb[4];
  #pragma unroll
  for (int mi = 0; mi < 4; ++mi){
    int r = wr * 64 + mi * 16 + (lane & 15);
    a_rb[mi] = r * 64 + ((gq ^ ((r >> 1) & 3)) << 4);
  }
  int b_site[8];
  #pragma unroll
  for (int ni = 0; ni < 8; ++ni)
    b_site[ni] = (wc * 2 + (ni >> 2)) * 72 + (ni & 3) * 16 + (lane & 15);

  #define STAGE(IT)                                                                 \
    {                                                                               \
      const int dhb = (IT) >> 3;                                                    \
      const int ic0s = ((IT) & 7) * 32;                                             \
      const unsigned short* ybase = ytb + (ptrdiff_t)(dhb - 1) * HP * CIN + ic0s;   \
      _Pragma("unroll")                                                             \
      for (int s = 0; s < 5; ++s)                                                   \
        if (y_has[s]) gload_lds16(ybase + y_go[s], &Yt[0] + y_lo[s]);               \
      const unsigned short* atap = nwb + (size_t)(dhb * 3) * COUT * CIN + ic0s;     \
      _Pragma("unroll")                                                             \
      for (int s = 0; s < 6; ++s)                                                   \
        gload_lds16(atap + (size_t)a_tap[s] * COUT * CIN + a_go[s], &Wa[0] + a_lo[s]); \
    }

  #define COMPUTE()                                                                 \
    {                                                                               \
      const char* wap = (const char*)&Wa[0];                                        \
      const char* ytp = (const char*)&Yt[0];                                        \
      _Pragma("unroll")                                                             \
      for (int tap = 0; tap < 3; ++tap){                                            \
        short8 af[4];                                                               \
        _Pragma("unroll")                                                           \
        for (int mi = 0; mi < 4; ++mi)                                              \
          af[mi] = *(const short8*)(wap + tap * 8192 + a_rb[mi]);                   \
        _Pragma("unroll")                                                           \
        for (int ni = 0; ni < 8; ++ni){                                             \
          const int site = b_site[ni] + tap;                                        \
          const int boff = (site << 6) + ((gq ^ ((site >> 1) & 3)) << 4);           \
          const short8 bf = *(const short8*)(ytp + boff);                           \
          _Pragma("unroll")                                                         \
          for (int mi = 0; mi < 4; ++mi)                                            \
            acc[mi][ni] = __builtin_amdgcn_mfma_f32_16x16x32_bf16(af[mi], bf, acc[mi][ni], 0, 0, 0); \
        }                                                                           \
      }                                                                             \
    }

  #pragma unroll 1
  for (int it = 0; it < 24; ++it){
    __syncthreads();     // previous compute done; safe to overwrite LDS
    STAGE(it);
    __syncthreads();     // DMA drained
    COMPUTE();
  }
  #undef STAGE
  #undef COMPUTE

  // epilogue: D layout col=lane&15 (hw), row=(lane>>4)*4+reg (oc)
  const int col_l = lane & 15, row_l = (lane >> 4) * 4;
  #pragma unroll
  for (int mi = 0; mi < 4; ++mi){
    #pragma unroll
    for (int r = 0; r < 4; ++r){
      const int ocl = wr * 64 + mi * 16 + row_l + r;
      const float bb = bsh[ocl];
      float* op = out + ((size_t)(b * COUT + oc0 + ocl)) * (HH * WW) + hw0 + wc * 128;
      #pragma unroll
      for (int ni = 0; ni < 8; ++ni)
        op[(ni >> 2) * 64 + (ni & 3) * 16 + col_l] = acc[mi][ni][r] + bb;
    }
  }
}

extern "C" void kernel_launch(void* const* d_in, const int* in_sizes, int n_in,
                              void* d_out, int out_size, void* d_ws, size_t ws_size,
                              hipStream_t stream){
  const float* y      = (const float*)d_in[0];
  const float* finger = (const float*)d_in[1];
  const float* ow     = (const float*)d_in[2];
  const float* wmask  = (const float*)d_in[3];
  const float* fwgt   = (const float*)d_in[4];
  const float* sw1    = (const float*)d_in[5];
  const float* sw2    = (const float*)d_in[6];
  const float* obias  = (const float*)d_in[7];
  const float* bmask  = (const float*)d_in[8];
  const float* fbias  = (const float*)d_in[9];
  const float* bw1    = (const float*)d_in[10];
  const float* bw2    = (const float*)d_in[11];
  float* out = (float*)d_out;
  float* ws  = (float*)d_ws;

  float* stat  = ws + OFF_STAT;
  float* bmean = ws + OFF_BMEAN;
  float* bstd  = ws + OFF_BSTD;
  float* C     = ws + OFF_C;
  float* style = ws + OFF_STYLE;
  float* nbias = ws + OFF_NBIAS;
  unsigned short* nw   = (unsigned short*)(ws + OFF_NW);
  unsigned short* ytrp = (unsigned short*)(ws + OFF_YTR);

  k_prep1<<<NB_CF + NB_SB + NB_YT, 256, 0, stream>>>(y, ytrp, ow, fwgt, wmask, C,
                                                     finger, sw1, sw2, style,
                                                     bw1, bw2, fbias, bmask, obias, nbias);
  k_wstats<<<B, 256, 0, stream>>>(C, style, stat, bmean, bstd);
  k_new_weight4<<<dim3(B / 2, COUT), 256, 0, stream>>>(ow, fwgt, wmask, style, stat, bmean, bstd, nw);
  k_conv_mfma11<<<512, 256, 0, stream>>>(ytrp, nw, nbias, out);
}

// Round 20
// 132.316 us; speedup vs baseline: 1.7385x; 1.0482x over previous
//
#include <hip/hip_runtime.h>
#include <math.h>

#define LSLOPE 0.01f

__device__ __forceinline__ float lrelu(float x){ return x >= 0.f ? x : LSLOPE * x; }

typedef __attribute__((ext_vector_type(8))) short short8;
typedef __attribute__((ext_vector_type(4))) float f32x4;

__device__ __forceinline__ unsigned short f2bf(float f){
  union { float f; unsigned u; } v; v.f = f;
  unsigned r = v.u + 0x7FFFu + ((v.u >> 16) & 1u);
  return (unsigned short)(r >> 16);
}

__device__ __forceinline__ void gload_lds16(const unsigned short* g, unsigned short* l){
  __builtin_amdgcn_global_load_lds((const __attribute__((address_space(1))) unsigned int*)(g),
                                   (__attribute__((address_space(3))) unsigned int*)(l), 16, 0, 0);
}

constexpr int B    = 16;
constexpr int CIN  = 256;
constexpr int COUT = 256;
constexpr int HH   = 64;
constexpr int WW   = 64;
constexpr int FD   = 128;
constexpr int LAT  = 128;
constexpr int WPS  = CIN * 9;           // 2304
constexpr int WTOT = COUT * WPS;        // 589824
constexpr int HP   = 66;                // padded spatial dim

// ---- workspace layout (in floats) ----
constexpr int OFF_STAT  = 0;                        // [2]
constexpr int OFF_BMEAN = 16;                       // [16]
constexpr int OFF_BSTD  = 32;                       // [16]
constexpr int OFF_P     = 64;                       // [11][8][2304] partials
constexpr int OFF_C     = OFF_P + 11 * 8 * WPS;     // [11][2304]
constexpr int OFF_STYLE = OFF_C + 11 * WPS;         // [16*4608]
constexpr int OFF_NBIAS = OFF_STYLE + B * 2 * WPS;  // [16*256]
constexpr int OFF_NW    = OFF_NBIAS + B * COUT;     // bf16 [16][9][256][256]
constexpr int OFF_YTR   = OFF_NW + (B * 9 * COUT * CIN) / 2;   // bf16 [16][66][66][256]

constexpr int PADT = 264;
constexpr int NB_YT = HP * B;        // 1056 (first: the HBM long pole)
constexpr int NB_CF = 72;            // 9 rem-blocks x 8 oc-chunks
constexpr int NB_SB = B * 18 + B;    // 304

// ---------- fused prep1: y transpose | coeff partials -> P | style MLP + bias ----------
__global__ __launch_bounds__(256) void k_prep1(const float* __restrict__ y, unsigned short* __restrict__ ytrp,
                                               const float* __restrict__ ow, const float* __restrict__ fwgt,
                                               const float* __restrict__ wmask, float* __restrict__ P,
                                               const float* __restrict__ finger, const float* __restrict__ sw1,
                                               const float* __restrict__ sw2, float* __restrict__ style,
                                               const float* __restrict__ bw1, const float* __restrict__ bw2,
                                               const float* __restrict__ fbias, const float* __restrict__ bmask,
                                               const float* __restrict__ obias, float* __restrict__ nbias){
  __shared__ __align__(16) char shraw[64 * PADT * 2];   // 33792 B
  const int blk = blockIdx.x;
  const int tid = threadIdx.x;

  if (blk < NB_YT){
    // ---- y -> channel-last bf16 with zero halo ----
    unsigned short* t = (unsigned short*)shraw;
    const int ghp = blk % HP, b = blk / HP;
    unsigned short* dst = ytrp + ((size_t)b * HP + ghp) * HP * CIN;
    if (ghp == 0 || ghp == HP - 1){
      for (int c = tid; c < HP * CIN / 8; c += 256) ((uint4*)dst)[c] = (uint4){0, 0, 0, 0};
      return;
    }
    const int h = ghp - 1;
    const float* src = y + (size_t)b * CIN * HH * WW + h * WW;
    #pragma unroll
    for (int k = 0; k < 16; ++k){
      int idx = tid + k * 256;
      int ic = idx >> 4, w4 = (idx & 15) * 4;
      float4 v = *(const float4*)(src + (size_t)ic * HH * WW + w4);
      t[(w4 + 0) * PADT + ic] = f2bf(v.x);
      t[(w4 + 1) * PADT + ic] = f2bf(v.y);
      t[(w4 + 2) * PADT + ic] = f2bf(v.z);
      t[(w4 + 3) * PADT + ic] = f2bf(v.w);
    }
    __syncthreads();
    for (int c = tid; c < HP * CIN / 8; c += 256){
      int gwp = c >> 5, icg = (c & 31) * 8;
      uint4 v = (uint4){0, 0, 0, 0};
      if (gwp >= 1 && gwp <= 64) v = *(const uint4*)(&t[(gwp - 1) * PADT + icg]);
      ((uint4*)dst)[c] = v;
    }
  } else if (blk < NB_YT + NB_CF){
    // ---- coefficient partials over a 32-oc chunk (r12-proven shape) ----
    const int cb = blk - NB_YT;           // 0..71
    const int rb = cb % 9, ob = cb / 9;
    const int rem = rb * 256 + tid;
    const int ic = rem / 9;
    float a_ow = 0.f, q_ow = 0.f, ab = 0.f, qb = 0.f;
    float a1 = 0.f, a2 = 0.f, d1 = 0.f, d2 = 0.f, d3 = 0.f, d4 = 0.f, d5 = 0.f;
    for (int oc = ob * 32; oc < ob * 32 + 32; ++oc){
      float w = ow[(size_t)oc * WPS + rem];
      float f = fwgt[(size_t)oc * WPS + rem];
      float m = wmask[oc * CIN + ic];
      float fw = (6.f - fminf(fmaxf(m, 0.f), 6.f)) * (1.f / 6.f);
      float base = w + fw * (f - w);
      float c1 = fw * f, c2 = fw;
      a_ow += w; q_ow += w * w;
      ab += base; qb += base * base;
      a1 += c1; a2 += c2;
      d1 += c1 * c1; d2 += c2 * c2; d3 += base * c1; d4 += base * c2; d5 += c1 * c2;
    }
    float* p = P + (size_t)ob * WPS + rem;
    p[(size_t)0  * 8 * WPS] = a_ow; p[(size_t)1  * 8 * WPS] = q_ow;
    p[(size_t)2  * 8 * WPS] = ab;   p[(size_t)3  * 8 * WPS] = qb;
    p[(size_t)4  * 8 * WPS] = a1;   p[(size_t)5  * 8 * WPS] = a2;
    p[(size_t)6  * 8 * WPS] = d1;   p[(size_t)7  * 8 * WPS] = d2;
    p[(size_t)8  * 8 * WPS] = d3;   p[(size_t)9  * 8 * WPS] = d4;
    p[(size_t)10 * 8 * WPS] = d5;
  } else {
    // ---- style MLP / bias ----
    float* sh = (float*)shraw;
    const int blk2 = blk - NB_YT - NB_CF;
    if (blk2 < B * 18){
      const int b = blk2 / 18, j0 = (blk2 - b * 18) * 256;
      if (tid < LAT){
        float a = 0.f;
        const float* fg = finger + b * FD;
        const float* w = sw1 + (size_t)tid * FD;
        for (int f = 0; f < FD; ++f) a += fg[f] * w[f];
        sh[tid] = lrelu(a);
      }
      __syncthreads();
      const int j = j0 + tid;
      float a = 0.f;
      const float* w2 = sw2 + (size_t)j * LAT;
      for (int l = 0; l < LAT; ++l) a += sh[l] * w2[l];
      style[(size_t)b * 2 * WPS + j] = a;
    } else {
      const int b = blk2 - B * 18, o = tid;
      float acc = 0.f;
      for (int f = 0; f < FD; ++f) acc += finger[b * FD + f] * bw1[o * FD + f];
      sh[o] = lrelu(acc);
      __syncthreads();
      float t = 0.f;
      for (int c = 0; c < COUT; ++c) t += sh[c] * bw2[o * COUT + c];
      t = lrelu(t);
      float sb = fbias[o] * t;
      float fwb = (6.f - fminf(fmaxf(bmask[o], 0.f), 6.f)) * (1.f / 6.f);
      nbias[b * COUT + o] = (1.f - fwb) * obias[o] + fwb * sb;
    }
  }
}

// ---------- reduce P -> C (r9-proven, trivial, 9 blocks) ----------
__global__ void k_coeff_r(const float* __restrict__ P, float* __restrict__ C){
  const int rem = blockIdx.x * 256 + threadIdx.x;
  #pragma unroll
  for (int a = 0; a < 11; ++a){
    float v = 0.f;
    #pragma unroll
    for (int ob = 0; ob < 8; ++ob) v += P[((size_t)a * 8 + ob) * WPS + rem];
    C[(size_t)a * WPS + rem] = v;
  }
}

// ---------- per-b stats from coefficients (champion version, reads C) ----------
__global__ __launch_bounds__(256) void k_wstats(const float* __restrict__ C, const float* __restrict__ style,
                                                float* stat, float* bmean, float* bstd){
  __shared__ float rs[4][4];
  const int b = blockIdx.x, tid = threadIdx.x;
  const int lane = tid & 63, wid = tid >> 6;
  const float* st = style + (size_t)b * 2 * WPS;
  float s = 0.f, q = 0.f, so = 0.f, qo = 0.f;
  for (int k = 0; k < 9; ++k){
    int rem = k * 256 + tid;
    float aow = C[0 * WPS + rem], qow = C[1 * WPS + rem];
    float ab  = C[2 * WPS + rem], qb  = C[3 * WPS + rem];
    float a1  = C[4 * WPS + rem], a2  = C[5 * WPS + rem];
    float d1  = C[6 * WPS + rem], d2  = C[7 * WPS + rem];
    float d3  = C[8 * WPS + rem], d4  = C[9 * WPS + rem], d5 = C[10 * WPS + rem];
    float s0 = st[rem], s1 = st[WPS + rem];
    so += aow; qo += qow;
    s += ab + s0 * a1 + s1 * a2;
    q += qb + s0 * s0 * d1 + s1 * s1 * d2 + 2.f * (s0 * d3 + s1 * d4 + s0 * s1 * d5);
  }
  for (int o = 32; o > 0; o >>= 1){
    s += __shfl_down(s, o); q += __shfl_down(q, o);
    so += __shfl_down(so, o); qo += __shfl_down(qo, o);
  }
  if (lane == 0){ rs[0][wid] = s; rs[1][wid] = q; rs[2][wid] = so; rs[3][wid] = qo; }
  __syncthreads();
  if (tid == 0){
    const float N = (float)WTOT;
    float S = rs[0][0] + rs[0][1] + rs[0][2] + rs[0][3];
    float Q = rs[1][0] + rs[1][1] + rs[1][2] + rs[1][3];
    bmean[b] = S / N;
    bstd[b]  = sqrtf((Q - S * S / N) / (N - 1.f));
    if (b == 0){
      float SO = rs[2][0] + rs[2][1] + rs[2][2] + rs[2][3];
      float QO = rs[3][0] + rs[3][1] + rs[3][2] + rs[3][3];
      stat[0] = SO / N;
      stat[1] = sqrtf((QO - SO * SO / N) / (N - 1.f));
    }
  }
}

// ---------- materialize new_weight bf16 [b][t][oc][ic]; 2 samples per block ----------
__global__ __launch_bounds__(256) void k_new_weight4(const float* __restrict__ ow, const float* __restrict__ fwgt,
                                                     const float* __restrict__ wmask, const float* __restrict__ style,
                                                     const float* __restrict__ stat, const float* __restrict__ bmean,
                                                     const float* __restrict__ bstd, unsigned short* __restrict__ nw){
  __shared__ float ows[WPS];
  __shared__ float fws[WPS];
  __shared__ float sts[2 * WPS];
  const int bi = blockIdx.x, oc = blockIdx.y;
  const int tid = threadIdx.x;               // = ic
  const float mean_ori = stat[0], std_ori = stat[1];
  const float4* owr4 = (const float4*)(ow + (size_t)oc * WPS);
  const float4* fwr4 = (const float4*)(fwgt + (size_t)oc * WPS);
  #pragma unroll
  for (int i = 0; i < 3; ++i){
    int idx = tid + i * 256;
    if (idx < WPS / 4){
      ((float4*)ows)[idx] = owr4[idx];
      ((float4*)fws)[idx] = fwr4[idx];
    }
  }
  const float fw = (6.f - fminf(fmaxf(wmask[oc * CIN + tid], 0.f), 6.f)) * (1.f / 6.f);
  #pragma unroll
  for (int bb = 0; bb < 2; ++bb){
    const int b = bi * 2 + bb;
    __syncthreads();
    const float4* st4 = (const float4*)(style + (size_t)b * 2 * WPS);
    #pragma unroll
    for (int i = 0; i < 5; ++i){
      int idx = tid + i * 256;
      if (idx < 2 * WPS / 4) ((float4*)sts)[idx] = st4[idx];
    }
    __syncthreads();
    const float bm = bmean[b], bs = bstd[b];
    #pragma unroll
    for (int t = 0; t < 9; ++t){
      int rem = tid * 9 + t;
      float owv = ows[rem];
      float sw = fws[rem] * (sts[rem] + 1.f) + sts[WPS + rem];
      float w1 = owv + fw * (sw - owv);
      float w2 = (w1 - bm) / bs * std_ori + mean_ori;
      nw[((size_t)(b * 9 + t) * COUT + oc) * CIN + tid] = f2bf(owv + fw * (w2 - owv));
    }
  }
}

// ---------- MFMA conv: 128oc x 256hw block, 64x128/wave, single-buffer LDS ----------
// Proven champion (r12/r14/r17/r19): 2 blocks/CU, XCD b-pinning, DMA staging, XOR swizzle.
__global__ __launch_bounds__(256, 2) void k_conv_mfma11(const unsigned short* __restrict__ ytrp,
                                                        const unsigned short* __restrict__ nw,
                                                        const float* __restrict__ nbias,
                                                        float* __restrict__ out){
  __shared__ __align__(16) unsigned short Wa[3 * 128 * 32];   // 24576 B
  __shared__ __align__(16) unsigned short Yt[288 * 32];       // 18432 B
  __shared__ float bsh[128];

  const int bid = blockIdx.x;
  const int xcd = bid & 7;
  const int b   = ((bid >> 8) << 3) | xcd;   // 0..15, pinned to xcd
  const int oc0 = ((bid >> 3) & 1) * 128;
  const int hwt = (bid >> 4) & 15;
  const int tid = threadIdx.x;
  const int lane = tid & 63, wid = tid >> 6;
  const int wr = wid >> 1, wc = wid & 1;   // wr: oc half (64), wc: hw half (128)
  const int hw0 = hwt * 256;
  const int h0  = hwt * 4;

  if (tid < 128) bsh[tid] = nbias[b * COUT + oc0 + tid];

  f32x4 acc[4][8];
  #pragma unroll
  for (int i = 0; i < 4; ++i)
    #pragma unroll
    for (int j = 0; j < 8; ++j) acc[i][j] = (f32x4){0.f, 0.f, 0.f, 0.f};

  const unsigned short* nwb = nw + ((size_t)(b * 9) * COUT + oc0) * CIN;
  const unsigned short* ytb = ytrp + (size_t)b * HP * HP * CIN;

  // ---- A DMA: 24 issues of 16 rows; wave takes I = wid + 4s, s<6 ----
  int a_tap[6], a_go[6], a_lo[6];
  #pragma unroll
  for (int s = 0; s < 6; ++s){
    int I = wid + 4 * s;
    int tap = I >> 3, rowbase = (I & 7) * 16;
    int row = rowbase + (lane >> 2), p = lane & 3;
    int g = p ^ ((row >> 1) & 3);
    a_tap[s] = tap;
    a_go[s]  = row * CIN + g * 8;
    a_lo[s]  = (tap * 128 + rowbase) * 32;
  }
  // ---- Y DMA: 288 sites (4 rows x 72), 18 issues of 16; I = wid + 4s, s<5 ----
  int y_go[5], y_lo[5]; bool y_has[5];
  #pragma unroll
  for (int s = 0; s < 5; ++s){
    int I = wid + 4 * s;
    y_has[s] = (I < 18);
    int Ic = y_has[s] ? I : 0;
    int site = Ic * 16 + (lane >> 2);
    int srow = site / 72;
    int scol = site - srow * 72;
    int gwp  = scol > 65 ? 65 : scol;
    int p = lane & 3, g = p ^ ((site >> 1) & 3);
    y_go[s] = ((h0 + srow + 1) * HP + gwp) * CIN + g * 8;
    y_lo[s] = Ic * 16 * 32;
  }

  // ---- fragment read bases ----
  const int gq = lane >> 4;
  int a_rb[4];
  #pragma unroll
  for (int mi = 0; mi < 4; ++mi){
    int r = wr * 64 + mi * 16 + (lane & 15);
    a_rb[mi] = r * 64 + ((gq ^ ((r >> 1) & 3)) << 4);
  }
  int b_site[8];
  #pragma unroll
  for (int ni = 0; ni < 8; ++ni)
    b_site[ni] = (wc * 2 + (ni >> 2)) * 72 + (ni & 3) * 16 + (lane & 15);

  #define STAGE(IT)                                                                 \
    {                                                                               \
      const int dhb = (IT) >> 3;                                                    \
      const int ic0s = ((IT) & 7) * 32;                                             \
      const unsigned short* ybase = ytb + (ptrdiff_t)(dhb - 1) * HP * CIN + ic0s;   \
      _Pragma("unroll")                                                             \
      for (int s = 0; s < 5; ++s)                                                   \
        if (y_has[s]) gload_lds16(ybase + y_go[s], &Yt[0] + y_lo[s]);               \
      const unsigned short* atap = nwb + (size_t)(dhb * 3) * COUT * CIN + ic0s;     \
      _Pragma("unroll")                                                             \
      for (int s = 0; s < 6; ++s)                                                   \
        gload_lds16(atap + (size_t)a_tap[s] * COUT * CIN + a_go[s], &Wa[0] + a_lo[s]); \
    }

  #define COMPUTE()                                                                 \
    {                                                                               \
      const char* wap = (const char*)&Wa[0];                                        \
      const char* ytp = (const char*)&Yt[0];                                        \
      _Pragma("unroll")                                                             \
      for (int tap = 0; tap < 3; ++tap){                                            \
        short8 af[4];                                                               \
        _Pragma("unroll")                                                           \
        for (int mi = 0; mi < 4; ++mi)                                              \
          af[mi] = *(const short8*)(wap + tap * 8192 + a_rb[mi]);                   \
        _Pragma("unroll")                                                           \
        for (int ni = 0; ni < 8; ++ni){                                             \
          const int site = b_site[ni] + tap;                                        \
          const int boff = (site << 6) + ((gq ^ ((site >> 1) & 3)) << 4);           \
          const short8 bf = *(const short8*)(ytp + boff);                           \
          _Pragma("unroll")                                                         \
          for (int mi = 0; mi < 4; ++mi)                                            \
            acc[mi][ni] = __builtin_amdgcn_mfma_f32_16x16x32_bf16(af[mi], bf, acc[mi][ni], 0, 0, 0); \
        }                                                                           \
      }                                                                             \
    }

  #pragma unroll 1
  for (int it = 0; it < 24; ++it){
    __syncthreads();     // previous compute done; safe to overwrite LDS
    STAGE(it);
    __syncthreads();     // DMA drained
    COMPUTE();
  }
  #undef STAGE
  #undef COMPUTE

  // epilogue: D layout col=lane&15 (hw), row=(lane>>4)*4+reg (oc)
  const int col_l = lane & 15, row_l = (lane >> 4) * 4;
  #pragma unroll
  for (int mi = 0; mi < 4; ++mi){
    #pragma unroll
    for (int r = 0; r < 4; ++r){
      const int ocl = wr * 64 + mi * 16 + row_l + r;
      const float bb = bsh[ocl];
      float* op = out + ((size_t)(b * COUT + oc0 + ocl)) * (HH * WW) + hw0 + wc * 128;
      #pragma unroll
      for (int ni = 0; ni < 8; ++ni)
        op[(ni >> 2) * 64 + (ni & 3) * 16 + col_l] = acc[mi][ni][r] + bb;
    }
  }
}

extern "C" void kernel_launch(void* const* d_in, const int* in_sizes, int n_in,
                              void* d_out, int out_size, void* d_ws, size_t ws_size,
                              hipStream_t stream){
  const float* y      = (const float*)d_in[0];
  const float* finger = (const float*)d_in[1];
  const float* ow     = (const float*)d_in[2];
  const float* wmask  = (const float*)d_in[3];
  const float* fwgt   = (const float*)d_in[4];
  const float* sw1    = (const float*)d_in[5];
  const float* sw2    = (const float*)d_in[6];
  const float* obias  = (const float*)d_in[7];
  const float* bmask  = (const float*)d_in[8];
  const float* fbias  = (const float*)d_in[9];
  const float* bw1    = (const float*)d_in[10];
  const float* bw2    = (const float*)d_in[11];
  float* out = (float*)d_out;
  float* ws  = (float*)d_ws;

  float* stat  = ws + OFF_STAT;
  float* bmean = ws + OFF_BMEAN;
  float* bstd  = ws + OFF_BSTD;
  float* P     = ws + OFF_P;
  float* C     = ws + OFF_C;
  float* style = ws + OFF_STYLE;
  float* nbias = ws + OFF_NBIAS;
  unsigned short* nw   = (unsigned short*)(ws + OFF_NW);
  unsigned short* ytrp = (unsigned short*)(ws + OFF_YTR);

  k_prep1<<<NB_YT + NB_CF + NB_SB, 256, 0, stream>>>(y, ytrp, ow, fwgt, wmask, P,
                                                     finger, sw1, sw2, style,
                                                     bw1, bw2, fbias, bmask, obias, nbias);
  k_coeff_r<<<9, 256, 0, stream>>>(P, C);
  k_wstats<<<B, 256, 0, stream>>>(C, style, stat, bmean, bstd);
  k_new_weight4<<<dim3(B / 2, COUT), 256, 0, stream>>>(ow, fwgt, wmask, style, stat, bmean, bstd, nw);
  k_conv_mfma11<<<512, 256, 0, stream>>>(ytrp, nw, nbias, out);
}

// Round 21
// 129.094 us; speedup vs baseline: 1.7819x; 1.0250x over previous
//
#include <hip/hip_runtime.h>
#include <math.h>

#define LSLOPE 0.01f

__device__ __forceinline__ float lrelu(float x){ return x >= 0.f ? x : LSLOPE * x; }

typedef __attribute__((ext_vector_type(8))) short short8;
typedef __attribute__((ext_vector_type(4))) float f32x4;

__device__ __forceinline__ unsigned short f2bf(float f){
  union { float f; unsigned u; } v; v.f = f;
  unsigned r = v.u + 0x7FFFu + ((v.u >> 16) & 1u);
  return (unsigned short)(r >> 16);
}

__device__ __forceinline__ void gload_lds16(const unsigned short* g, unsigned short* l){
  __builtin_amdgcn_global_load_lds((const __attribute__((address_space(1))) unsigned int*)(g),
                                   (__attribute__((address_space(3))) unsigned int*)(l), 16, 0, 0);
}

constexpr int B    = 16;
constexpr int CIN  = 256;
constexpr int COUT = 256;
constexpr int HH   = 64;
constexpr int WW   = 64;
constexpr int FD   = 128;
constexpr int LAT  = 128;
constexpr int WPS  = CIN * 9;           // 2304
constexpr int WTOT = COUT * WPS;        // 589824
constexpr int HP   = 66;                // padded spatial dim

// ---- workspace layout (in floats) ----
constexpr int OFF_STAT  = 0;                        // [2]
constexpr int OFF_BMEAN = 16;                       // [16]
constexpr int OFF_BSTD  = 32;                       // [16]
constexpr int OFF_P     = 64;                       // [11][8][2304] partials
constexpr int OFF_C     = OFF_P + 11 * 8 * WPS;     // [11][2304]
constexpr int OFF_STYLE = OFF_C + 11 * WPS;         // [16*4608]
constexpr int OFF_NBIAS = OFF_STYLE + B * 2 * WPS;  // [16*256]
constexpr int OFF_NW    = OFF_NBIAS + B * COUT;     // bf16 [16][9][256][256]
constexpr int OFF_YTR   = OFF_NW + (B * 9 * COUT * CIN) / 2;   // bf16 [16][66][66][256]

constexpr int PADT = 264;
constexpr int NB_YT = HP * B;        // 1056 (first: the HBM long pole)
constexpr int NB_CF = 72;            // 9 rem-blocks x 8 oc-chunks
constexpr int NB_SB = B * 18 + B;    // 304

// ---------- fused prep1: y transpose | coeff partials -> P | style MLP + bias ----------
__global__ __launch_bounds__(256) void k_prep1(const float* __restrict__ y, unsigned short* __restrict__ ytrp,
                                               const float* __restrict__ ow, const float* __restrict__ fwgt,
                                               const float* __restrict__ wmask, float* __restrict__ P,
                                               const float* __restrict__ finger, const float* __restrict__ sw1,
                                               const float* __restrict__ sw2, float* __restrict__ style,
                                               const float* __restrict__ bw1, const float* __restrict__ bw2,
                                               const float* __restrict__ fbias, const float* __restrict__ bmask,
                                               const float* __restrict__ obias, float* __restrict__ nbias){
  __shared__ __align__(16) char shraw[64 * PADT * 2];   // 33792 B
  const int blk = blockIdx.x;
  const int tid = threadIdx.x;

  if (blk < NB_YT){
    // ---- y -> channel-last bf16 with zero halo ----
    unsigned short* t = (unsigned short*)shraw;
    const int ghp = blk % HP, b = blk / HP;
    unsigned short* dst = ytrp + ((size_t)b * HP + ghp) * HP * CIN;
    if (ghp == 0 || ghp == HP - 1){
      for (int c = tid; c < HP * CIN / 8; c += 256) ((uint4*)dst)[c] = (uint4){0, 0, 0, 0};
      return;
    }
    const int h = ghp - 1;
    const float* src = y + (size_t)b * CIN * HH * WW + h * WW;
    #pragma unroll
    for (int k = 0; k < 16; ++k){
      int idx = tid + k * 256;
      int ic = idx >> 4, w4 = (idx & 15) * 4;
      float4 v = *(const float4*)(src + (size_t)ic * HH * WW + w4);
      t[(w4 + 0) * PADT + ic] = f2bf(v.x);
      t[(w4 + 1) * PADT + ic] = f2bf(v.y);
      t[(w4 + 2) * PADT + ic] = f2bf(v.z);
      t[(w4 + 3) * PADT + ic] = f2bf(v.w);
    }
    __syncthreads();
    for (int c = tid; c < HP * CIN / 8; c += 256){
      int gwp = c >> 5, icg = (c & 31) * 8;
      uint4 v = (uint4){0, 0, 0, 0};
      if (gwp >= 1 && gwp <= 64) v = *(const uint4*)(&t[(gwp - 1) * PADT + icg]);
      ((uint4*)dst)[c] = v;
    }
  } else if (blk < NB_YT + NB_CF){
    // ---- coefficient partials over a 32-oc chunk ----
    const int cb = blk - NB_YT;           // 0..71
    const int rb = cb % 9, ob = cb / 9;
    const int rem = rb * 256 + tid;
    const int ic = rem / 9;
    float a_ow = 0.f, q_ow = 0.f, ab = 0.f, qb = 0.f;
    float a1 = 0.f, a2 = 0.f, d1 = 0.f, d2 = 0.f, d3 = 0.f, d4 = 0.f, d5 = 0.f;
    for (int oc = ob * 32; oc < ob * 32 + 32; ++oc){
      float w = ow[(size_t)oc * WPS + rem];
      float f = fwgt[(size_t)oc * WPS + rem];
      float m = wmask[oc * CIN + ic];
      float fw = (6.f - fminf(fmaxf(m, 0.f), 6.f)) * (1.f / 6.f);
      float base = w + fw * (f - w);
      float c1 = fw * f, c2 = fw;
      a_ow += w; q_ow += w * w;
      ab += base; qb += base * base;
      a1 += c1; a2 += c2;
      d1 += c1 * c1; d2 += c2 * c2; d3 += base * c1; d4 += base * c2; d5 += c1 * c2;
    }
    float* p = P + (size_t)ob * WPS + rem;
    p[(size_t)0  * 8 * WPS] = a_ow; p[(size_t)1  * 8 * WPS] = q_ow;
    p[(size_t)2  * 8 * WPS] = ab;   p[(size_t)3  * 8 * WPS] = qb;
    p[(size_t)4  * 8 * WPS] = a1;   p[(size_t)5  * 8 * WPS] = a2;
    p[(size_t)6  * 8 * WPS] = d1;   p[(size_t)7  * 8 * WPS] = d2;
    p[(size_t)8  * 8 * WPS] = d3;   p[(size_t)9  * 8 * WPS] = d4;
    p[(size_t)10 * 8 * WPS] = d5;
  } else {
    // ---- style MLP / bias ----
    float* sh = (float*)shraw;
    const int blk2 = blk - NB_YT - NB_CF;
    if (blk2 < B * 18){
      const int b = blk2 / 18, j0 = (blk2 - b * 18) * 256;
      if (tid < LAT){
        float a = 0.f;
        const float* fg = finger + b * FD;
        const float* w = sw1 + (size_t)tid * FD;
        for (int f = 0; f < FD; ++f) a += fg[f] * w[f];
        sh[tid] = lrelu(a);
      }
      __syncthreads();
      const int j = j0 + tid;
      float a = 0.f;
      const float* w2 = sw2 + (size_t)j * LAT;
      for (int l = 0; l < LAT; ++l) a += sh[l] * w2[l];
      style[(size_t)b * 2 * WPS + j] = a;
    } else {
      const int b = blk2 - B * 18, o = tid;
      float acc = 0.f;
      for (int f = 0; f < FD; ++f) acc += finger[b * FD + f] * bw1[o * FD + f];
      sh[o] = lrelu(acc);
      __syncthreads();
      float t = 0.f;
      for (int c = 0; c < COUT; ++c) t += sh[c] * bw2[o * COUT + c];
      t = lrelu(t);
      float sb = fbias[o] * t;
      float fwb = (6.f - fminf(fmaxf(bmask[o], 0.f), 6.f)) * (1.f / 6.f);
      nbias[b * COUT + o] = (1.f - fwb) * obias[o] + fwb * sb;
    }
  }
}

// ---------- reduce P -> C (trivial, 9 blocks) ----------
__global__ void k_coeff_r(const float* __restrict__ P, float* __restrict__ C){
  const int rem = blockIdx.x * 256 + threadIdx.x;
  #pragma unroll
  for (int a = 0; a < 11; ++a){
    float v = 0.f;
    #pragma unroll
    for (int ob = 0; ob < 8; ++ob) v += P[((size_t)a * 8 + ob) * WPS + rem];
    C[(size_t)a * WPS + rem] = v;
  }
}

// ---------- per-b stats from coefficients ----------
__global__ __launch_bounds__(256) void k_wstats(const float* __restrict__ C, const float* __restrict__ style,
                                                float* stat, float* bmean, float* bstd){
  __shared__ float rs[4][4];
  const int b = blockIdx.x, tid = threadIdx.x;
  const int lane = tid & 63, wid = tid >> 6;
  const float* st = style + (size_t)b * 2 * WPS;
  float s = 0.f, q = 0.f, so = 0.f, qo = 0.f;
  for (int k = 0; k < 9; ++k){
    int rem = k * 256 + tid;
    float aow = C[0 * WPS + rem], qow = C[1 * WPS + rem];
    float ab  = C[2 * WPS + rem], qb  = C[3 * WPS + rem];
    float a1  = C[4 * WPS + rem], a2  = C[5 * WPS + rem];
    float d1  = C[6 * WPS + rem], d2  = C[7 * WPS + rem];
    float d3  = C[8 * WPS + rem], d4  = C[9 * WPS + rem], d5 = C[10 * WPS + rem];
    float s0 = st[rem], s1 = st[WPS + rem];
    so += aow; qo += qow;
    s += ab + s0 * a1 + s1 * a2;
    q += qb + s0 * s0 * d1 + s1 * s1 * d2 + 2.f * (s0 * d3 + s1 * d4 + s0 * s1 * d5);
  }
  for (int o = 32; o > 0; o >>= 1){
    s += __shfl_down(s, o); q += __shfl_down(q, o);
    so += __shfl_down(so, o); qo += __shfl_down(qo, o);
  }
  if (lane == 0){ rs[0][wid] = s; rs[1][wid] = q; rs[2][wid] = so; rs[3][wid] = qo; }
  __syncthreads();
  if (tid == 0){
    const float N = (float)WTOT;
    float S = rs[0][0] + rs[0][1] + rs[0][2] + rs[0][3];
    float Q = rs[1][0] + rs[1][1] + rs[1][2] + rs[1][3];
    bmean[b] = S / N;
    bstd[b]  = sqrtf((Q - S * S / N) / (N - 1.f));
    if (b == 0){
      float SO = rs[2][0] + rs[2][1] + rs[2][2] + rs[2][3];
      float QO = rs[3][0] + rs[3][1] + rs[3][2] + rs[3][3];
      stat[0] = SO / N;
      stat[1] = sqrtf((QO - SO * SO / N) / (N - 1.f));
    }
  }
}

// ---------- materialize new_weight bf16 [b][t][oc][ic]; 4 samples per block ----------
// float4-vectorized staging; ow/fwgt staged once per block, reused for 4 samples.
__global__ __launch_bounds__(256) void k_new_weight4(const float* __restrict__ ow, const float* __restrict__ fwgt,
                                                     const float* __restrict__ wmask, const float* __restrict__ style,
                                                     const float* __restrict__ stat, const float* __restrict__ bmean,
                                                     const float* __restrict__ bstd, unsigned short* __restrict__ nw){
  __shared__ float ows[WPS];
  __shared__ float fws[WPS];
  __shared__ float sts[2 * WPS];
  const int bi = blockIdx.x, oc = blockIdx.y;
  const int tid = threadIdx.x;               // = ic
  const float mean_ori = stat[0], std_ori = stat[1];
  const float4* owr4 = (const float4*)(ow + (size_t)oc * WPS);
  const float4* fwr4 = (const float4*)(fwgt + (size_t)oc * WPS);
  #pragma unroll
  for (int i = 0; i < 3; ++i){                 // 576 float4 total, 256 threads
    int idx = tid + i * 256;
    if (idx < WPS / 4){
      ((float4*)ows)[idx] = owr4[idx];
      ((float4*)fws)[idx] = fwr4[idx];
    }
  }
  const float fw = (6.f - fminf(fmaxf(wmask[oc * CIN + tid], 0.f), 6.f)) * (1.f / 6.f);
  #pragma unroll 1
  for (int bb = 0; bb < 4; ++bb){
    const int b = bi * 4 + bb;
    __syncthreads();
    const float4* st4 = (const float4*)(style + (size_t)b * 2 * WPS);
    #pragma unroll
    for (int i = 0; i < 5; ++i){               // 1152 float4 total
      int idx = tid + i * 256;
      if (idx < 2 * WPS / 4) ((float4*)sts)[idx] = st4[idx];
    }
    __syncthreads();
    const float bm = bmean[b], bs = bstd[b];
    #pragma unroll
    for (int t = 0; t < 9; ++t){
      int rem = tid * 9 + t;
      float owv = ows[rem];
      float sw = fws[rem] * (sts[rem] + 1.f) + sts[WPS + rem];
      float w1 = owv + fw * (sw - owv);
      float w2 = (w1 - bm) / bs * std_ori + mean_ori;
      nw[((size_t)(b * 9 + t) * COUT + oc) * CIN + tid] = f2bf(owv + fw * (w2 - owv));
    }
  }
}

// ---------- MFMA conv: 128oc x 256hw block, 64x128/wave, single-buffer LDS ----------
// Proven champion: 2 blocks/CU, XCD b-pinning, DMA staging, XOR chunk swizzle.
__global__ __launch_bounds__(256, 2) void k_conv_mfma11(const unsigned short* __restrict__ ytrp,
                                                        const unsigned short* __restrict__ nw,
                                                        const float* __restrict__ nbias,
                                                        float* __restrict__ out){
  __shared__ __align__(16) unsigned short Wa[3 * 128 * 32];   // 24576 B
  __shared__ __align__(16) unsigned short Yt[288 * 32];       // 18432 B
  __shared__ float bsh[128];

  const int bid = blockIdx.x;
  const int xcd = bid & 7;
  const int b   = ((bid >> 8) << 3) | xcd;   // 0..15, pinned to xcd
  const int oc0 = ((bid >> 3) & 1) * 128;
  const int hwt = (bid >> 4) & 15;
  const int tid = threadIdx.x;
  const int lane = tid & 63, wid = tid >> 6;
  const int wr = wid >> 1, wc = wid & 1;   // wr: oc half (64), wc: hw half (128)
  const int hw0 = hwt * 256;
  const int h0  = hwt * 4;

  if (tid < 128) bsh[tid] = nbias[b * COUT + oc0 + tid];

  f32x4 acc[4][8];
  #pragma unroll
  for (int i = 0; i < 4; ++i)
    #pragma unroll
    for (int j = 0; j < 8; ++j) acc[i][j] = (f32x4){0.f, 0.f, 0.f, 0.f};

  const unsigned short* nwb = nw + ((size_t)(b * 9) * COUT + oc0) * CIN;
  const unsigned short* ytb = ytrp + (size_t)b * HP * HP * CIN;

  // ---- A DMA: 24 issues of 16 rows; wave takes I = wid + 4s, s<6 ----
  int a_tap[6], a_go[6], a_lo[6];
  #pragma unroll
  for (int s = 0; s < 6; ++s){
    int I = wid + 4 * s;
    int tap = I >> 3, rowbase = (I & 7) * 16;
    int row = rowbase + (lane >> 2), p = lane & 3;
    int g = p ^ ((row >> 1) & 3);
    a_tap[s] = tap;
    a_go[s]  = row * CIN + g * 8;
    a_lo[s]  = (tap * 128 + rowbase) * 32;
  }
  // ---- Y DMA: 288 sites (4 rows x 72), 18 issues of 16; I = wid + 4s, s<5 ----
  int y_go[5], y_lo[5]; bool y_has[5];
  #pragma unroll
  for (int s = 0; s < 5; ++s){
    int I = wid + 4 * s;
    y_has[s] = (I < 18);
    int Ic = y_has[s] ? I : 0;
    int site = Ic * 16 + (lane >> 2);
    int srow = site / 72;
    int scol = site - srow * 72;
    int gwp  = scol > 65 ? 65 : scol;
    int p = lane & 3, g = p ^ ((site >> 1) & 3);
    y_go[s] = ((h0 + srow + 1) * HP + gwp) * CIN + g * 8;
    y_lo[s] = Ic * 16 * 32;
  }

  // ---- fragment read bases ----
  const int gq = lane >> 4;
  int a_rb[4];
  #pragma unroll
  for (int mi = 0; mi < 4; ++mi){
    int r = wr * 64 + mi * 16 + (lane & 15);
    a_rb[mi] = r * 64 + ((gq ^ ((r >> 1) & 3)) << 4);
  }
  int b_site[8];
  #pragma unroll
  for (int ni = 0; ni < 8; ++ni)
    b_site[ni] = (wc * 2 + (ni >> 2)) * 72 + (ni & 3) * 16 + (lane & 15);

  #define STAGE(IT)                                                                 \
    {                                                                               \
      const int dhb = (IT) >> 3;                                                    \
      const int ic0s = ((IT) & 7) * 32;                                             \
      const unsigned short* ybase = ytb + (ptrdiff_t)(dhb - 1) * HP * CIN + ic0s;   \
      _Pragma("unroll")                                                             \
      for (int s = 0; s < 5; ++s)                                                   \
        if (y_has[s]) gload_lds16(ybase + y_go[s], &Yt[0] + y_lo[s]);               \
      const unsigned short* atap = nwb + (size_t)(dhb * 3) * COUT * CIN + ic0s;     \
      _Pragma("unroll")                                                             \
      for (int s = 0; s < 6; ++s)                                                   \
        gload_lds16(atap + (size_t)a_tap[s] * COUT * CIN + a_go[s], &Wa[0] + a_lo[s]); \
    }

  #define COMPUTE()                                                                 \
    {                                                                               \
      const char* wap = (const char*)&Wa[0];                                        \
      const char* ytp = (const char*)&Yt[0];                                        \
      _Pragma("unroll")                                                             \
      for (int tap = 0; tap < 3; ++tap){                                            \
        short8 af[4];                                                               \
        _Pragma("unroll")                                                           \
        for (int mi = 0; mi < 4; ++mi)                                              \
          af[mi] = *(const short8*)(wap + tap * 8192 + a_rb[mi]);                   \
        _Pragma("unroll")                                                           \
        for (int ni = 0; ni < 8; ++ni){                                             \
          const int site = b_site[ni] + tap;                                        \
          const int boff = (site << 6) + ((gq ^ ((site >> 1) & 3)) << 4);           \
          const short8 bf = *(const short8*)(ytp + boff);                           \
          _Pragma("unroll")                                                         \
          for (int mi = 0; mi < 4; ++mi)                                            \
            acc[mi][ni] = __builtin_amdgcn_mfma_f32_16x16x32_bf16(af[mi], bf, acc[mi][ni], 0, 0, 0); \
        }                                                                           \
      }                                                                             \
    }

  #pragma unroll 1
  for (int it = 0; it < 24; ++it){
    __syncthreads();     // previous compute done; safe to overwrite LDS
    STAGE(it);
    __syncthreads();     // DMA drained
    COMPUTE();
  }
  #undef STAGE
  #undef COMPUTE

  // epilogue: D layout col=lane&15 (hw), row=(lane>>4)*4+reg (oc)
  const int col_l = lane & 15, row_l = (lane >> 4) * 4;
  #pragma unroll
  for (int mi = 0; mi < 4; ++mi){
    #pragma unroll
    for (int r = 0; r < 4; ++r){
      const int ocl = wr * 64 + mi * 16 + row_l + r;
      const float bb = bsh[ocl];
      float* op = out + ((size_t)(b * COUT + oc0 + ocl)) * (HH * WW) + hw0 + wc * 128;
      #pragma unroll
      for (int ni = 0; ni < 8; ++ni)
        op[(ni >> 2) * 64 + (ni & 3) * 16 + col_l] = acc[mi][ni][r] + bb;
    }
  }
}

extern "C" void kernel_launch(void* const* d_in, const int* in_sizes, int n_in,
                              void* d_out, int out_size, void* d_ws, size_t ws_size,
                              hipStream_t stream){
  const float* y      = (const float*)d_in[0];
  const float* finger = (const float*)d_in[1];
  const float* ow     = (const float*)d_in[2];
  const float* wmask  = (const float*)d_in[3];
  const float* fwgt   = (const float*)d_in[4];
  const float* sw1    = (const float*)d_in[5];
  const float* sw2    = (const float*)d_in[6];
  const float* obias  = (const float*)d_in[7];
  const float* bmask  = (const float*)d_in[8];
  const float* fbias  = (const float*)d_in[9];
  const float* bw1    = (const float*)d_in[10];
  const float* bw2    = (const float*)d_in[11];
  float* out = (float*)d_out;
  float* ws  = (float*)d_ws;

  float* stat  = ws + OFF_STAT;
  float* bmean = ws + OFF_BMEAN;
  float* bstd  = ws + OFF_BSTD;
  float* P     = ws + OFF_P;
  float* C     = ws + OFF_C;
  float* style = ws + OFF_STYLE;
  float* nbias = ws + OFF_NBIAS;
  unsigned short* nw   = (unsigned short*)(ws + OFF_NW);
  unsigned short* ytrp = (unsigned short*)(ws + OFF_YTR);

  k_prep1<<<NB_YT + NB_CF + NB_SB, 256, 0, stream>>>(y, ytrp, ow, fwgt, wmask, P,
                                                     finger, sw1, sw2, style,
                                                     bw1, bw2, fbias, bmask, obias, nbias);
  k_coeff_r<<<9, 256, 0, stream>>>(P, C);
  k_wstats<<<B, 256, 0, stream>>>(C, style, stat, bmean, bstd);
  k_new_weight4<<<dim3(B / 4, COUT), 256, 0, stream>>>(ow, fwgt, wmask, style, stat, bmean, bstd, nw);
  k_conv_mfma11<<<512, 256, 0, stream>>>(ytrp, nw, nbias, out);
}